// Round 1
// baseline (3257.656 us; speedup 1.0000x reference)
//
#include <hip/hip_runtime.h>

#define NN 100000
#define NE 1600000

// ---------------- graph prep ----------------
__global__ void k_deg(const int* __restrict__ col, int* __restrict__ degi) {
  int e = blockIdx.x * blockDim.x + threadIdx.x;
  if (e < NE) atomicAdd(&degi[col[e]], 1);
}

__global__ void k_dis(const int* __restrict__ degi, float* __restrict__ dis) {
  int i = blockIdx.x * blockDim.x + threadIdx.x;
  if (i < NN) {
    int d = degi[i];
    dis[i] = d > 0 ? rsqrtf((float)d) : 0.0f;
  }
}

// single-block exclusive scan of degi -> off (N=100000 fits easily)
__global__ void k_scan(const int* __restrict__ degi, int* __restrict__ off) {
  __shared__ int sums[1024];
  const int CH = (NN + 1023) / 1024;  // 98
  int t = threadIdx.x;
  int s0 = t * CH;
  int s1 = min(s0 + CH, NN);
  int s = 0;
  for (int i = s0; i < s1; ++i) s += degi[i];
  sums[t] = s;
  __syncthreads();
  for (int o = 1; o < 1024; o <<= 1) {
    int v = (t >= o) ? sums[t - o] : 0;
    __syncthreads();
    sums[t] += v;
    __syncthreads();
  }
  int pre = (t == 0) ? 0 : sums[t - 1];
  for (int i = s0; i < s1; ++i) {
    off[i] = pre;
    pre += degi[i];
  }
  if (t == 0) off[NN] = sums[1023];
}

__global__ void k_fill(const int* __restrict__ row, const int* __restrict__ col,
                       const float* __restrict__ dis, const int* __restrict__ off,
                       int* __restrict__ cursor, int* __restrict__ src,
                       float* __restrict__ wgt) {
  int e = blockIdx.x * blockDim.x + threadIdx.x;
  if (e < NE) {
    int c = col[e], r = row[e];
    int slot = off[c] + atomicAdd(&cursor[c], 1);
    src[slot] = r;
    wgt[slot] = dis[r] * dis[c];
  }
}

// ---------------- propagation (segmented gather-reduce, no atomics) ----------------
template <int F>
__global__ void k_prop_small(const float* __restrict__ h, const int* __restrict__ off,
                             const int* __restrict__ src, const float* __restrict__ wgt,
                             float* __restrict__ out) {
  int node = blockIdx.x;
  int t = threadIdx.x;  // 64 threads, first F active
  if (t >= F) return;
  int b = off[node], e = off[node + 1];
  float acc = 0.f;
  for (int j = b; j < e; ++j) acc += h[src[j] * F + t] * wgt[j];
  out[node * F + t] = acc;
}

__global__ void k_prop128(const float* __restrict__ h, const int* __restrict__ off,
                          const int* __restrict__ src, const float* __restrict__ wgt,
                          float* __restrict__ out) {
  int node = blockIdx.x;
  int t = threadIdx.x;  // 128
  int b = off[node], e = off[node + 1];
  float acc = 0.f;
  for (int j = b; j < e; ++j) acc += h[src[j] * 128 + t] * wgt[j];
  out[node * 128 + t] = acc;
}

// ---------------- dense GEMMs ----------------
// C[M x 128] (op)= A[M x IN] @ W[IN x 128] (+ bias) (relu). IN % 4 == 0. M = 100000.
template <int IN, bool ACCUM, bool BIAS, bool RELU>
__global__ __launch_bounds__(256) void k_mm128(const float* __restrict__ A,
                                               const float* __restrict__ W,
                                               const float* __restrict__ bias,
                                               float* __restrict__ C) {
  __shared__ float Wl[IN][128];
  for (int i = threadIdx.x * 4; i < IN * 128; i += 1024)
    *(float4*)&((float*)Wl)[i] = *(const float4*)&W[i];
  __syncthreads();
  int r0 = blockIdx.x * 32 + (threadIdx.x >> 5) * 4;
  int c0 = (threadIdx.x & 31) * 4;
  float acc[4][4] = {};
  for (int k = 0; k < IN; k += 4) {
    float4 w0 = *(const float4*)&Wl[k][c0];
    float4 w1 = *(const float4*)&Wl[k + 1][c0];
    float4 w2 = *(const float4*)&Wl[k + 2][c0];
    float4 w3 = *(const float4*)&Wl[k + 3][c0];
#pragma unroll
    for (int i = 0; i < 4; ++i) {
      float4 a = *(const float4*)&A[(r0 + i) * IN + k];
      acc[i][0] = fmaf(a.x, w0.x, fmaf(a.y, w1.x, fmaf(a.z, w2.x, fmaf(a.w, w3.x, acc[i][0]))));
      acc[i][1] = fmaf(a.x, w0.y, fmaf(a.y, w1.y, fmaf(a.z, w2.y, fmaf(a.w, w3.y, acc[i][1]))));
      acc[i][2] = fmaf(a.x, w0.z, fmaf(a.y, w1.z, fmaf(a.z, w2.z, fmaf(a.w, w3.z, acc[i][2]))));
      acc[i][3] = fmaf(a.x, w0.w, fmaf(a.y, w1.w, fmaf(a.z, w2.w, fmaf(a.w, w3.w, acc[i][3]))));
    }
  }
#pragma unroll
  for (int i = 0; i < 4; ++i) {
    float4 v = make_float4(acc[i][0], acc[i][1], acc[i][2], acc[i][3]);
    float* cp = &C[(r0 + i) * 128 + c0];
    if (BIAS) {
      v.x += bias[c0 + 0]; v.y += bias[c0 + 1]; v.z += bias[c0 + 2]; v.w += bias[c0 + 3];
    }
    if (ACCUM) {
      float4 o = *(const float4*)cp;
      v.x += o.x; v.y += o.y; v.z += o.z; v.w += o.w;
    }
    if (RELU) {
      v.x = fmaxf(v.x, 0.f); v.y = fmaxf(v.y, 0.f);
      v.z = fmaxf(v.z, 0.f); v.w = fmaxf(v.w, 0.f);
    }
    *(float4*)cp = v;
  }
}

// C[M x 16] (op)= A[M x IN] @ W[IN x 16] (+ bias). block 256 = 16 rows x 16 cols.
template <int IN, bool ACCUM, bool BIAS>
__global__ void k_mm16(const float* __restrict__ A, const float* __restrict__ W,
                       const float* __restrict__ bias, float* __restrict__ C) {
  __shared__ float Wl[IN * 16];
  for (int i = threadIdx.x; i < IN * 16; i += 256) Wl[i] = W[i];
  __syncthreads();
  int r = blockIdx.x * 16 + (threadIdx.x >> 4);
  int c = threadIdx.x & 15;
  float acc = 0.f;
  for (int k = 0; k < IN; ++k) acc += A[r * IN + k] * Wl[k * 16 + c];
  int idx = r * 16 + c;
  if (BIAS) acc += bias[c];
  if (ACCUM) acc += C[idx];
  C[idx] = acc;
}

// out[n] = dot(h[n,:128], w) + b ; one 64-lane wave per node
__global__ void k_fc(const float* __restrict__ h, const float* __restrict__ w,
                     const float* __restrict__ b, float* __restrict__ out) {
  int node = blockIdx.x;
  int t = threadIdx.x;  // 64
  float s = h[node * 128 + t] * w[t] + h[node * 128 + t + 64] * w[t + 64];
  for (int o = 32; o; o >>= 1) s += __shfl_down(s, o);
  if (t == 0) out[node] = s + b[0];
}

extern "C" void kernel_launch(void* const* d_in, const int* in_sizes, int n_in,
                              void* d_out, int out_size, void* d_ws, size_t ws_size,
                              hipStream_t stream) {
  const float* x = (const float*)d_in[0];
  const int* ei = (const int*)d_in[1];
  const float* fe_ws = (const float*)d_in[2];
  const float* fe_b = (const float*)d_in[3];
  const float* c0_ws = (const float*)d_in[4];
  const float* c0_b = (const float*)d_in[5];
  const float* cw = (const float*)d_in[6];
  const float* cb = (const float*)d_in[7];
  const float* fcw = (const float*)d_in[8];
  const float* fcb = (const float*)d_in[9];
  float* out = (float*)d_out;

  const int* row = ei;       // edge_index[0]
  const int* colv = ei + NE; // edge_index[1]

  char* wp = (char*)d_ws;
  auto alloc = [&](size_t bytes) {
    char* p = wp;
    wp += (bytes + 511) & ~(size_t)511;
    return p;
  };
  int* degi = (int*)alloc(NN * 4);
  int* off = (int*)alloc((NN + 1) * 4);
  int* cursor = (int*)alloc(NN * 4);
  float* dis = (float*)alloc(NN * 4);
  int* src = (int*)alloc((size_t)NE * 4);
  float* wgt = (float*)alloc((size_t)NE * 4);
  float* B1 = (float*)alloc((size_t)NN * 128 * 4);
  float* B2 = (float*)alloc((size_t)NN * 128 * 4);
  float* B3 = (float*)alloc((size_t)NN * 128 * 4);
  // small buffers overlaid in B2 (B2 first written at conv layer 1)
  float* px17 = B2;
  float* h16 = B2 + (size_t)NN * 17;
  float* p16a = h16 + (size_t)NN * 16;
  float* p16b = p16a + (size_t)NN * 16;

  // ---- graph prep ----
  hipMemsetAsync(degi, 0, NN * 4, stream);
  hipMemsetAsync(cursor, 0, NN * 4, stream);
  k_deg<<<(NE + 255) / 256, 256, 0, stream>>>(colv, degi);
  k_dis<<<(NN + 255) / 256, 256, 0, stream>>>(degi, dis);
  k_scan<<<1, 1024, 0, stream>>>(degi, off);
  k_fill<<<(NE + 255) / 256, 256, 0, stream>>>(row, colv, dis, off, cursor, src, wgt);

  // ---- featureEmbedding: h16 = x@fe_ws0 + prop(x)@fe_ws1 + fe_b ----
  k_mm16<17, false, true><<<NN / 16, 256, 0, stream>>>(x, fe_ws, fe_b, h16);
  k_prop_small<17><<<NN, 64, 0, stream>>>(x, off, src, wgt, px17);
  k_mm16<17, true, false><<<NN / 16, 256, 0, stream>>>(px17, fe_ws + 17 * 16, nullptr, h16);

  // ---- conv0 (16 -> 128, K=3, relu) -> B1 ----
  k_mm128<16, false, true, false><<<NN / 32, 256, 0, stream>>>(h16, c0_ws, c0_b, B1);
  k_prop_small<16><<<NN, 64, 0, stream>>>(h16, off, src, wgt, p16a);
  k_mm128<16, true, false, false><<<NN / 32, 256, 0, stream>>>(p16a, c0_ws + 2048, nullptr, B1);
  k_prop_small<16><<<NN, 64, 0, stream>>>(p16a, off, src, wgt, p16b);
  k_mm128<16, true, false, false><<<NN / 32, 256, 0, stream>>>(p16b, c0_ws + 4096, nullptr, B1);
  k_prop_small<16><<<NN, 64, 0, stream>>>(p16b, off, src, wgt, p16a);
  k_mm128<16, true, false, true><<<NN / 32, 256, 0, stream>>>(p16a, c0_ws + 6144, nullptr, B1);

  // ---- conv1..3 (128 -> 128, K=3) ----
  float* bufs[3] = {B1, B2, B3};
  int ih = 0;
  for (int l = 0; l < 3; ++l) {
    const float* Wb = cw + (size_t)l * 4 * 128 * 128;
    const float* bl = cb + l * 128;
    int ia = (ih + 1) % 3, ip = (ih + 2) % 3;
    float* hin = bufs[ih];
    float* acc = bufs[ia];
    float* tmp = bufs[ip];
    k_mm128<128, false, true, false><<<NN / 32, 256, 0, stream>>>(hin, Wb, bl, acc);
    k_prop128<<<NN, 128, 0, stream>>>(hin, off, src, wgt, tmp);
    k_mm128<128, true, false, false><<<NN / 32, 256, 0, stream>>>(tmp, Wb + 16384, nullptr, acc);
    k_prop128<<<NN, 128, 0, stream>>>(tmp, off, src, wgt, hin);
    k_mm128<128, true, false, false><<<NN / 32, 256, 0, stream>>>(hin, Wb + 32768, nullptr, acc);
    k_prop128<<<NN, 128, 0, stream>>>(hin, off, src, wgt, tmp);
    if (l < 2)
      k_mm128<128, true, false, true><<<NN / 32, 256, 0, stream>>>(tmp, Wb + 49152, nullptr, acc);
    else
      k_mm128<128, true, false, false><<<NN / 32, 256, 0, stream>>>(tmp, Wb + 49152, nullptr, acc);
    ih = ia;
  }

  // ---- fc: out = h @ fc_w + fc_b ----
  k_fc<<<NN, 64, 0, stream>>>(bufs[ih], fcw, fcb, out);
}

// Round 2
// 1634.201 us; speedup vs baseline: 1.9934x; 1.9934x over previous
//
#include <hip/hip_runtime.h>

#define NN 100000
#define NE 1600000

typedef _Float16 half8 __attribute__((ext_vector_type(8)));
typedef float f32x4 __attribute__((ext_vector_type(4)));
struct h2s { _Float16 x, y; };
struct h4s { _Float16 a, b, c, d; };

// ---------------- graph prep ----------------
__global__ void k_deg(const int* __restrict__ col, int* __restrict__ degi) {
  int e = blockIdx.x * blockDim.x + threadIdx.x;
  if (e < NE) atomicAdd(&degi[col[e]], 1);
}

__global__ void k_dis(const int* __restrict__ degi, float* __restrict__ dis) {
  int i = blockIdx.x * blockDim.x + threadIdx.x;
  if (i < NN) {
    int d = degi[i];
    dis[i] = d > 0 ? rsqrtf((float)d) : 0.0f;
  }
}

__global__ void k_scan(const int* __restrict__ degi, int* __restrict__ off) {
  __shared__ int sums[1024];
  const int CH = (NN + 1023) / 1024;
  int t = threadIdx.x;
  int s0 = t * CH;
  int s1 = min(s0 + CH, NN);
  int s = 0;
  for (int i = s0; i < s1; ++i) s += degi[i];
  sums[t] = s;
  __syncthreads();
  for (int o = 1; o < 1024; o <<= 1) {
    int v = (t >= o) ? sums[t - o] : 0;
    __syncthreads();
    sums[t] += v;
    __syncthreads();
  }
  int pre = (t == 0) ? 0 : sums[t - 1];
  for (int i = s0; i < s1; ++i) {
    off[i] = pre;
    pre += degi[i];
  }
  if (t == 0) off[NN] = sums[1023];
}

__global__ void k_fill(const int* __restrict__ row, const int* __restrict__ col,
                       const float* __restrict__ dis, const int* __restrict__ off,
                       int* __restrict__ cursor, int* __restrict__ src,
                       float* __restrict__ wgt) {
  int e = blockIdx.x * blockDim.x + threadIdx.x;
  if (e < NE) {
    int c = col[e], r = row[e];
    int slot = off[c] + atomicAdd(&cursor[c], 1);
    src[slot] = r;
    wgt[slot] = dis[r] * dis[c];
  }
}

// convert+transpose conv weights: cw [12][128k][128n] f32 -> wt [12][128n][128k] f16
__global__ void k_wprep(const float* __restrict__ cw, _Float16* __restrict__ wt) {
  int i = blockIdx.x * 256 + threadIdx.x;
  if (i < 12 * 16384) {
    int mat = i >> 14;
    int rem = i & 16383;
    int k = rem >> 7;
    int n = rem & 127;
    wt[(mat << 14) | (n << 7) | k] = (_Float16)cw[i];
  }
}

// ---------------- propagation ----------------
template <int F>
__global__ void k_prop_small(const float* __restrict__ h, const int* __restrict__ off,
                             const int* __restrict__ src, const float* __restrict__ wgt,
                             float* __restrict__ out) {
  int node = blockIdx.x;
  int t = threadIdx.x;
  if (t >= F) return;
  int b = off[node], e = off[node + 1];
  float acc = 0.f;
  for (int j = b; j < e; ++j) acc += h[src[j] * F + t] * wgt[j];
  out[node * F + t] = acc;
}

// fp16 128-wide: 64 threads, 2 features each, edge loop unrolled x4 for MLP
__global__ void k_prop128h(const h2s* __restrict__ h, const int* __restrict__ off,
                           const int* __restrict__ src, const float* __restrict__ wgt,
                           h2s* __restrict__ out) {
  int node = blockIdx.x;
  int t = threadIdx.x;  // 64
  int b = off[node], e = off[node + 1];
  float ax = 0.f, ay = 0.f;
  int j = b;
  for (; j + 4 <= e; j += 4) {
    int s0 = src[j], s1 = src[j + 1], s2 = src[j + 2], s3 = src[j + 3];
    float w0 = wgt[j], w1 = wgt[j + 1], w2 = wgt[j + 2], w3 = wgt[j + 3];
    h2s v0 = h[s0 * 64 + t];
    h2s v1 = h[s1 * 64 + t];
    h2s v2 = h[s2 * 64 + t];
    h2s v3 = h[s3 * 64 + t];
    ax = fmaf((float)v0.x, w0, fmaf((float)v1.x, w1, fmaf((float)v2.x, w2, fmaf((float)v3.x, w3, ax))));
    ay = fmaf((float)v0.y, w0, fmaf((float)v1.y, w1, fmaf((float)v2.y, w2, fmaf((float)v3.y, w3, ay))));
  }
  for (; j < e; ++j) {
    int s = src[j];
    float w = wgt[j];
    h2s v = h[s * 64 + t];
    ax = fmaf((float)v.x, w, ax);
    ay = fmaf((float)v.y, w, ay);
  }
  h2s o;
  o.x = (_Float16)ax;
  o.y = (_Float16)ay;
  out[node * 64 + t] = o;
}

// ---------------- fused TAG layer GEMM (128->128, 4 sources, MFMA f16) ----------------
// out[n][128] = relu?( sum_s A_s @ W_s + bias ), A_s fp16 [NN][128], Wt [4][128n][128k] f16
template <bool RELU>
__global__ __launch_bounds__(256) void k_tag4_mfma(
    const _Float16* __restrict__ A0, const _Float16* __restrict__ A1,
    const _Float16* __restrict__ A2, const _Float16* __restrict__ A3,
    const _Float16* __restrict__ Wt, const float* __restrict__ bias,
    _Float16* __restrict__ out) {
  int wid = threadIdx.x >> 6;
  int lane = threadIdx.x & 63;
  int m0 = blockIdx.x * 64 + wid * 16;
  int r = lane & 15, kg = lane >> 4;
  int ra_row = min(m0 + r, NN - 1);
  f32x4 acc[8] = {};
  const _Float16* As[4] = {A0, A1, A2, A3};
#pragma unroll
  for (int s = 0; s < 4; ++s) {
    const _Float16* A = As[s];
    const _Float16* W = Wt + (s << 14);
#pragma unroll
    for (int kc = 0; kc < 4; ++kc) {
      int kbase = kc * 32 + kg * 8;
      half8 a = *(const half8*)&A[(size_t)ra_row * 128 + kbase];
#pragma unroll
      for (int nb = 0; nb < 8; ++nb) {
        half8 b = *(const half8*)&W[((nb * 16 + r) << 7) + kbase];
        acc[nb] = __builtin_amdgcn_mfma_f32_16x16x32_f16(a, b, acc[nb], 0, 0, 0);
      }
    }
  }
  int crow0 = m0 + kg * 4;
  int ccol = lane & 15;
#pragma unroll
  for (int nb = 0; nb < 8; ++nb) {
    int col = nb * 16 + ccol;
    float bv = bias[col];
#pragma unroll
    for (int e = 0; e < 4; ++e) {
      float v = acc[nb][e] + bv;
      if (RELU) v = fmaxf(v, 0.f);
      int rr = crow0 + e;
      if (rr < NN) out[(size_t)rr * 128 + col] = (_Float16)v;
    }
  }
}

// ---------------- conv0 fused (4 fp32 sources 16-wide -> 128, relu, fp16 out) ----------------
__global__ __launch_bounds__(256) void k_conv0_fused(
    const float* __restrict__ A0, const float* __restrict__ A1,
    const float* __restrict__ A2, const float* __restrict__ A3,
    const float* __restrict__ W /*[4][16][128]*/, const float* __restrict__ bias,
    _Float16* __restrict__ out) {
  __shared__ float Wl[4 * 16 * 128];
  for (int i = threadIdx.x * 4; i < 4 * 16 * 128; i += 1024)
    *(float4*)&Wl[i] = *(const float4*)&W[i];
  __syncthreads();
  int r0 = blockIdx.x * 32 + (threadIdx.x >> 5) * 4;
  int c0 = (threadIdx.x & 31) * 4;
  float acc[4][4] = {};
  const float* As[4] = {A0, A1, A2, A3};
#pragma unroll
  for (int s = 0; s < 4; ++s) {
    const float* A = As[s];
    const float* Ws = &Wl[s * 2048];
#pragma unroll
    for (int k = 0; k < 16; k += 4) {
      float4 w0 = *(const float4*)&Ws[(k + 0) * 128 + c0];
      float4 w1 = *(const float4*)&Ws[(k + 1) * 128 + c0];
      float4 w2 = *(const float4*)&Ws[(k + 2) * 128 + c0];
      float4 w3 = *(const float4*)&Ws[(k + 3) * 128 + c0];
#pragma unroll
      for (int i = 0; i < 4; ++i) {
        float4 a = *(const float4*)&A[(r0 + i) * 16 + k];
        acc[i][0] = fmaf(a.x, w0.x, fmaf(a.y, w1.x, fmaf(a.z, w2.x, fmaf(a.w, w3.x, acc[i][0]))));
        acc[i][1] = fmaf(a.x, w0.y, fmaf(a.y, w1.y, fmaf(a.z, w2.y, fmaf(a.w, w3.y, acc[i][1]))));
        acc[i][2] = fmaf(a.x, w0.z, fmaf(a.y, w1.z, fmaf(a.z, w2.z, fmaf(a.w, w3.z, acc[i][2]))));
        acc[i][3] = fmaf(a.x, w0.w, fmaf(a.y, w1.w, fmaf(a.z, w2.w, fmaf(a.w, w3.w, acc[i][3]))));
      }
    }
  }
#pragma unroll
  for (int i = 0; i < 4; ++i) {
    h4s o;
    o.a = (_Float16)fmaxf(acc[i][0] + bias[c0 + 0], 0.f);
    o.b = (_Float16)fmaxf(acc[i][1] + bias[c0 + 1], 0.f);
    o.c = (_Float16)fmaxf(acc[i][2] + bias[c0 + 2], 0.f);
    o.d = (_Float16)fmaxf(acc[i][3] + bias[c0 + 3], 0.f);
    *(h4s*)&out[(size_t)(r0 + i) * 128 + c0] = o;
  }
}

// ---------------- feature embedding GEMM (fp32, 16-out) ----------------
template <int IN, bool ACCUM, bool BIAS>
__global__ void k_mm16(const float* __restrict__ A, const float* __restrict__ W,
                       const float* __restrict__ bias, float* __restrict__ C) {
  __shared__ float Wl[IN * 16];
  for (int i = threadIdx.x; i < IN * 16; i += 256) Wl[i] = W[i];
  __syncthreads();
  int r = blockIdx.x * 16 + (threadIdx.x >> 4);
  int c = threadIdx.x & 15;
  float acc = 0.f;
  for (int k = 0; k < IN; ++k) acc += A[r * IN + k] * Wl[k * 16 + c];
  int idx = r * 16 + c;
  if (BIAS) acc += bias[c];
  if (ACCUM) acc += C[idx];
  C[idx] = acc;
}

// out[n] = dot(h_fp16[n,:128], w_fp32) + b
__global__ void k_fc(const _Float16* __restrict__ h, const float* __restrict__ w,
                     const float* __restrict__ b, float* __restrict__ out) {
  int node = blockIdx.x;
  int t = threadIdx.x;  // 64
  float s = (float)h[node * 128 + t] * w[t] + (float)h[node * 128 + t + 64] * w[t + 64];
  for (int o = 32; o; o >>= 1) s += __shfl_down(s, o);
  if (t == 0) out[node] = s + b[0];
}

extern "C" void kernel_launch(void* const* d_in, const int* in_sizes, int n_in,
                              void* d_out, int out_size, void* d_ws, size_t ws_size,
                              hipStream_t stream) {
  const float* x = (const float*)d_in[0];
  const int* ei = (const int*)d_in[1];
  const float* fe_ws = (const float*)d_in[2];
  const float* fe_b = (const float*)d_in[3];
  const float* c0_ws = (const float*)d_in[4];
  const float* c0_b = (const float*)d_in[5];
  const float* cw = (const float*)d_in[6];
  const float* cb = (const float*)d_in[7];
  const float* fcw = (const float*)d_in[8];
  const float* fcb = (const float*)d_in[9];
  float* out = (float*)d_out;

  const int* row = ei;
  const int* colv = ei + NE;

  char* wp = (char*)d_ws;
  auto alloc = [&](size_t bytes) {
    char* p = wp;
    wp += (bytes + 511) & ~(size_t)511;
    return p;
  };
  int* degi = (int*)alloc(NN * 4);
  int* off = (int*)alloc((NN + 1) * 4);
  int* cursor = (int*)alloc(NN * 4);
  float* dis = (float*)alloc(NN * 4);
  int* src = (int*)alloc((size_t)NE * 4);
  float* wgt = (float*)alloc((size_t)NE * 4);
  _Float16* wsT = (_Float16*)alloc((size_t)12 * 16384 * 2);
  float* px17 = (float*)alloc((size_t)NN * 17 * 4);
  float* h16 = (float*)alloc((size_t)NN * 16 * 4);
  float* p16a = (float*)alloc((size_t)NN * 16 * 4);
  float* p16b = (float*)alloc((size_t)NN * 16 * 4);
  float* p16c = (float*)alloc((size_t)NN * 16 * 4);
  _Float16* H0 = (_Float16*)alloc((size_t)NN * 128 * 2);
  _Float16* H1 = (_Float16*)alloc((size_t)NN * 128 * 2);
  _Float16* T1 = (_Float16*)alloc((size_t)NN * 128 * 2);
  _Float16* T2 = (_Float16*)alloc((size_t)NN * 128 * 2);
  _Float16* T3 = (_Float16*)alloc((size_t)NN * 128 * 2);

  // ---- graph prep ----
  hipMemsetAsync(degi, 0, NN * 4, stream);
  hipMemsetAsync(cursor, 0, NN * 4, stream);
  k_deg<<<(NE + 255) / 256, 256, 0, stream>>>(colv, degi);
  k_dis<<<(NN + 255) / 256, 256, 0, stream>>>(degi, dis);
  k_scan<<<1, 1024, 0, stream>>>(degi, off);
  k_fill<<<(NE + 255) / 256, 256, 0, stream>>>(row, colv, dis, off, cursor, src, wgt);
  k_wprep<<<768, 256, 0, stream>>>(cw, wsT);

  // ---- featureEmbedding (fp32): h16 = x@W0 + prop(x)@W1 + b ----
  k_mm16<17, false, true><<<NN / 16, 256, 0, stream>>>(x, fe_ws, fe_b, h16);
  k_prop_small<17><<<NN, 64, 0, stream>>>(x, off, src, wgt, px17);
  k_mm16<17, true, false><<<NN / 16, 256, 0, stream>>>(px17, fe_ws + 17 * 16, nullptr, h16);

  // ---- conv0 (16 -> 128, K=3, relu) -> H0 fp16 ----
  k_prop_small<16><<<NN, 64, 0, stream>>>(h16, off, src, wgt, p16a);
  k_prop_small<16><<<NN, 64, 0, stream>>>(p16a, off, src, wgt, p16b);
  k_prop_small<16><<<NN, 64, 0, stream>>>(p16b, off, src, wgt, p16c);
  k_conv0_fused<<<NN / 32, 256, 0, stream>>>(h16, p16a, p16b, p16c, c0_ws, c0_b, H0);

  // ---- conv1..3 (128 -> 128, K=3): 3 props + 1 fused MFMA GEMM each ----
  _Float16* hin = H0;
  _Float16* hout = H1;
  int mgrid = (NN + 63) / 64;
  for (int l = 0; l < 3; ++l) {
    k_prop128h<<<NN, 64, 0, stream>>>((const h2s*)hin, off, src, wgt, (h2s*)T1);
    k_prop128h<<<NN, 64, 0, stream>>>((const h2s*)T1, off, src, wgt, (h2s*)T2);
    k_prop128h<<<NN, 64, 0, stream>>>((const h2s*)T2, off, src, wgt, (h2s*)T3);
    const _Float16* Wl = wsT + (size_t)l * 4 * 16384;
    const float* bl = cb + l * 128;
    if (l < 2)
      k_tag4_mfma<true><<<mgrid, 256, 0, stream>>>(hin, T1, T2, T3, Wl, bl, hout);
    else
      k_tag4_mfma<false><<<mgrid, 256, 0, stream>>>(hin, T1, T2, T3, Wl, bl, hout);
    _Float16* t = hin; hin = hout; hout = t;
  }

  // ---- fc ----
  k_fc<<<NN, 64, 0, stream>>>(hin, fcw, fcb, out);
}

// Round 3
// 1308.709 us; speedup vs baseline: 2.4892x; 1.2487x over previous
//
#include <hip/hip_runtime.h>

#define NN 100000
#define NE 1600000
#define SCAN_B 98  // ceil-ish: 98*1024 >= NN

typedef _Float16 half8 __attribute__((ext_vector_type(8)));
typedef float f32x4 __attribute__((ext_vector_type(4)));
struct h2s { _Float16 x, y; };
struct h4s { _Float16 a, b, c, d; };

// ---------------- graph prep ----------------
__global__ void k_deg(const int* __restrict__ col, int* __restrict__ degi) {
  int e = blockIdx.x * blockDim.x + threadIdx.x;
  if (e < NE) atomicAdd(&degi[col[e]], 1);
}

__global__ void k_dis(const int* __restrict__ degi, float* __restrict__ dis) {
  int i = blockIdx.x * blockDim.x + threadIdx.x;
  if (i < NN) {
    int d = degi[i];
    dis[i] = d > 0 ? rsqrtf((float)d) : 0.0f;
  }
}

// hierarchical scan: 1) per-block sums
__global__ void k_scan1(const int* __restrict__ degi, int* __restrict__ bsum) {
  __shared__ int red[256];
  int t = threadIdx.x;
  int base = blockIdx.x * 1024 + t * 4;
  int s = 0;
#pragma unroll
  for (int u = 0; u < 4; ++u) {
    int i = base + u;
    if (i < NN) s += degi[i];
  }
  red[t] = s;
  __syncthreads();
  for (int o = 128; o; o >>= 1) {
    if (t < o) red[t] += red[t + o];
    __syncthreads();
  }
  if (t == 0) bsum[blockIdx.x] = red[0];
}

// 2) exclusive scan of block sums (single small block) + total -> off[NN]
__global__ void k_scan2(const int* __restrict__ bsum, int* __restrict__ boff,
                        int* __restrict__ off) {
  __shared__ int sh[128];
  int t = threadIdx.x;  // 128
  int v = (t < SCAN_B) ? bsum[t] : 0;
  sh[t] = v;
  __syncthreads();
  for (int o = 1; o < 128; o <<= 1) {
    int u = (t >= o) ? sh[t - o] : 0;
    __syncthreads();
    sh[t] += u;
    __syncthreads();
  }
  if (t < SCAN_B) boff[t] = sh[t] - v;
  if (t == 127) off[NN] = sh[127];
}

// 3) finalize per-element offsets
__global__ void k_scan3(const int* __restrict__ degi, const int* __restrict__ boff,
                        int* __restrict__ off) {
  __shared__ int red[256];
  int t = threadIdx.x;
  int base = blockIdx.x * 1024 + t * 4;
  int d[4];
  int s = 0;
#pragma unroll
  for (int u = 0; u < 4; ++u) {
    int i = base + u;
    d[u] = (i < NN) ? degi[i] : 0;
    s += d[u];
  }
  red[t] = s;
  __syncthreads();
  for (int o = 1; o < 256; o <<= 1) {
    int u2 = (t >= o) ? red[t - o] : 0;
    __syncthreads();
    red[t] += u2;
    __syncthreads();
  }
  int pre = red[t] - s + boff[blockIdx.x];
#pragma unroll
  for (int u = 0; u < 4; ++u) {
    int i = base + u;
    if (i < NN) {
      off[i] = pre;
      pre += d[u];
    }
  }
}

__global__ void k_fill(const int* __restrict__ row, const int* __restrict__ col,
                       const float* __restrict__ dis, const int* __restrict__ off,
                       int* __restrict__ cursor, int* __restrict__ src,
                       float* __restrict__ wgt) {
  int e = blockIdx.x * blockDim.x + threadIdx.x;
  if (e < NE) {
    int c = col[e], r = row[e];
    int slot = off[c] + atomicAdd(&cursor[c], 1);
    src[slot] = r;
    wgt[slot] = dis[r] * dis[c];
  }
}

// convert+transpose conv weights: cw [12][128k][128n] f32 -> wt [12][128n][128k] f16
__global__ void k_wprep(const float* __restrict__ cw, _Float16* __restrict__ wt) {
  int i = blockIdx.x * 256 + threadIdx.x;
  if (i < 12 * 16384) {
    int mat = i >> 14;
    int rem = i & 16383;
    int k = rem >> 7;
    int n = rem & 127;
    wt[(mat << 14) | (n << 7) | k] = (_Float16)cw[i];
  }
}

// ---------------- propagation ----------------
// fp32, F features, one node per 64-thread block (used once for x, F=17)
template <int F>
__global__ void k_prop_small(const float* __restrict__ h, const int* __restrict__ off,
                             const int* __restrict__ src, const float* __restrict__ wgt,
                             float* __restrict__ out) {
  int node = blockIdx.x;
  int t = threadIdx.x;
  if (t >= F) return;
  int b = off[node], e = off[node + 1];
  float acc = 0.f;
  for (int j = b; j < e; ++j) acc += h[src[j] * F + t] * wgt[j];
  out[node * F + t] = acc;
}

// fp16 16-wide: 8 lanes per node (h2s each), 8 nodes per 64-thread block
__global__ void k_prop16h(const h2s* __restrict__ h, const int* __restrict__ off,
                          const int* __restrict__ src, const float* __restrict__ wgt,
                          h2s* __restrict__ out) {
  int t = threadIdx.x;  // 64
  int node = blockIdx.x * 8 + (t >> 3);
  int f = t & 7;
  int b = off[node], e = off[node + 1];
  float ax = 0.f, ay = 0.f;
  int j = b;
  for (; j + 2 <= e; j += 2) {
    int s0 = src[j], s1 = src[j + 1];
    float w0 = wgt[j], w1 = wgt[j + 1];
    h2s v0 = h[s0 * 8 + f];
    h2s v1 = h[s1 * 8 + f];
    ax = fmaf((float)v0.x, w0, fmaf((float)v1.x, w1, ax));
    ay = fmaf((float)v0.y, w0, fmaf((float)v1.y, w1, ay));
  }
  if (j < e) {
    int s = src[j];
    float w = wgt[j];
    h2s v = h[s * 8 + f];
    ax = fmaf((float)v.x, w, ax);
    ay = fmaf((float)v.y, w, ay);
  }
  h2s o;
  o.x = (_Float16)ax;
  o.y = (_Float16)ay;
  unsigned bits;
  __builtin_memcpy(&bits, &o, 4);
  __builtin_nontemporal_store(bits, (unsigned*)&out[node * 8 + f]);
}

// fp16 128-wide: 64 threads, h2s per thread, unroll x8
__global__ void k_prop128h(const h2s* __restrict__ h, const int* __restrict__ off,
                           const int* __restrict__ src, const float* __restrict__ wgt,
                           h2s* __restrict__ out) {
  int node = blockIdx.x;
  int t = threadIdx.x;  // 64
  int b = off[node], e = off[node + 1];
  float ax = 0.f, ay = 0.f;
  int j = b;
  for (; j + 8 <= e; j += 8) {
    h2s v[8];
    float w[8];
#pragma unroll
    for (int u = 0; u < 8; ++u) {
      v[u] = h[src[j + u] * 64 + t];
      w[u] = wgt[j + u];
    }
#pragma unroll
    for (int u = 0; u < 8; ++u) {
      ax = fmaf((float)v[u].x, w[u], ax);
      ay = fmaf((float)v[u].y, w[u], ay);
    }
  }
  for (; j < e; ++j) {
    int s = src[j];
    float w = wgt[j];
    h2s v = h[s * 64 + t];
    ax = fmaf((float)v.x, w, ax);
    ay = fmaf((float)v.y, w, ay);
  }
  h2s o;
  o.x = (_Float16)ax;
  o.y = (_Float16)ay;
  unsigned bits;
  __builtin_memcpy(&bits, &o, 4);
  __builtin_nontemporal_store(bits, (unsigned*)&out[node * 64 + t]);
}

// ---------------- fused TAG layer GEMM (128->128, 4 sources, MFMA f16) ----------------
template <bool RELU>
__global__ __launch_bounds__(256) void k_tag4_mfma(
    const _Float16* __restrict__ A0, const _Float16* __restrict__ A1,
    const _Float16* __restrict__ A2, const _Float16* __restrict__ A3,
    const _Float16* __restrict__ Wt, const float* __restrict__ bias,
    _Float16* __restrict__ out) {
  int wid = threadIdx.x >> 6;
  int lane = threadIdx.x & 63;
  int m0 = blockIdx.x * 64 + wid * 16;
  int r = lane & 15, kg = lane >> 4;
  int ra_row = min(m0 + r, NN - 1);
  f32x4 acc[8] = {};
  const _Float16* As[4] = {A0, A1, A2, A3};
#pragma unroll
  for (int s = 0; s < 4; ++s) {
    const _Float16* A = As[s];
    const _Float16* W = Wt + (s << 14);
#pragma unroll
    for (int kc = 0; kc < 4; ++kc) {
      int kbase = kc * 32 + kg * 8;
      half8 a = *(const half8*)&A[(size_t)ra_row * 128 + kbase];
#pragma unroll
      for (int nb = 0; nb < 8; ++nb) {
        half8 b = *(const half8*)&W[((nb * 16 + r) << 7) + kbase];
        acc[nb] = __builtin_amdgcn_mfma_f32_16x16x32_f16(a, b, acc[nb], 0, 0, 0);
      }
    }
  }
  int crow0 = m0 + kg * 4;
  int ccol = lane & 15;
#pragma unroll
  for (int nb = 0; nb < 8; ++nb) {
    int col = nb * 16 + ccol;
    float bv = bias[col];
#pragma unroll
    for (int e = 0; e < 4; ++e) {
      float v = acc[nb][e] + bv;
      if (RELU) v = fmaxf(v, 0.f);
      int rr = crow0 + e;
      if (rr < NN) out[(size_t)rr * 128 + col] = (_Float16)v;
    }
  }
}

// ---------------- conv0 fused (4 fp16 sources 16-wide -> 128, relu, fp16 out) ----------------
__global__ __launch_bounds__(256) void k_conv0_fused(
    const _Float16* __restrict__ A0, const _Float16* __restrict__ A1,
    const _Float16* __restrict__ A2, const _Float16* __restrict__ A3,
    const float* __restrict__ W /*[4][16][128]*/, const float* __restrict__ bias,
    _Float16* __restrict__ out) {
  __shared__ float Wl[4 * 16 * 128];
  for (int i = threadIdx.x * 4; i < 4 * 16 * 128; i += 1024)
    *(float4*)&Wl[i] = *(const float4*)&W[i];
  __syncthreads();
  int r0 = blockIdx.x * 32 + (threadIdx.x >> 5) * 4;
  int c0 = (threadIdx.x & 31) * 4;
  float acc[4][4] = {};
  const _Float16* As[4] = {A0, A1, A2, A3};
#pragma unroll
  for (int s = 0; s < 4; ++s) {
    const _Float16* A = As[s];
    const float* Ws = &Wl[s * 2048];
#pragma unroll
    for (int k = 0; k < 16; k += 4) {
      float4 w0 = *(const float4*)&Ws[(k + 0) * 128 + c0];
      float4 w1 = *(const float4*)&Ws[(k + 1) * 128 + c0];
      float4 w2 = *(const float4*)&Ws[(k + 2) * 128 + c0];
      float4 w3 = *(const float4*)&Ws[(k + 3) * 128 + c0];
#pragma unroll
      for (int i = 0; i < 4; ++i) {
        h4s a4 = *(const h4s*)&A[(r0 + i) * 16 + k];
        float ax = (float)a4.a, ay = (float)a4.b, az = (float)a4.c, aw = (float)a4.d;
        acc[i][0] = fmaf(ax, w0.x, fmaf(ay, w1.x, fmaf(az, w2.x, fmaf(aw, w3.x, acc[i][0]))));
        acc[i][1] = fmaf(ax, w0.y, fmaf(ay, w1.y, fmaf(az, w2.y, fmaf(aw, w3.y, acc[i][1]))));
        acc[i][2] = fmaf(ax, w0.z, fmaf(ay, w1.z, fmaf(az, w2.z, fmaf(aw, w3.z, acc[i][2]))));
        acc[i][3] = fmaf(ax, w0.w, fmaf(ay, w1.w, fmaf(az, w2.w, fmaf(aw, w3.w, acc[i][3]))));
      }
    }
  }
#pragma unroll
  for (int i = 0; i < 4; ++i) {
    h4s o;
    o.a = (_Float16)fmaxf(acc[i][0] + bias[c0 + 0], 0.f);
    o.b = (_Float16)fmaxf(acc[i][1] + bias[c0 + 1], 0.f);
    o.c = (_Float16)fmaxf(acc[i][2] + bias[c0 + 2], 0.f);
    o.d = (_Float16)fmaxf(acc[i][3] + bias[c0 + 3], 0.f);
    *(h4s*)&out[(size_t)(r0 + i) * 128 + c0] = o;
  }
}

// ---------------- feature embedding GEMM (fp32 in, fp16 out, 16 cols) ----------------
template <int IN, bool ACCUM, bool BIAS>
__global__ void k_mm16h(const float* __restrict__ A, const float* __restrict__ W,
                        const float* __restrict__ bias, _Float16* __restrict__ C) {
  __shared__ float Wl[IN * 16];
  for (int i = threadIdx.x; i < IN * 16; i += 256) Wl[i] = W[i];
  __syncthreads();
  int r = blockIdx.x * 16 + (threadIdx.x >> 4);
  int c = threadIdx.x & 15;
  float acc = 0.f;
  for (int k = 0; k < IN; ++k) acc += A[r * IN + k] * Wl[k * 16 + c];
  int idx = r * 16 + c;
  if (BIAS) acc += bias[c];
  if (ACCUM) acc += (float)C[idx];
  C[idx] = (_Float16)acc;
}

// out[n] = dot(h_fp16[n,:128], w_fp32) + b
__global__ void k_fc(const _Float16* __restrict__ h, const float* __restrict__ w,
                     const float* __restrict__ b, float* __restrict__ out) {
  int node = blockIdx.x;
  int t = threadIdx.x;  // 64
  float s = (float)h[node * 128 + t] * w[t] + (float)h[node * 128 + t + 64] * w[t + 64];
  for (int o = 32; o; o >>= 1) s += __shfl_down(s, o);
  if (t == 0) out[node] = s + b[0];
}

extern "C" void kernel_launch(void* const* d_in, const int* in_sizes, int n_in,
                              void* d_out, int out_size, void* d_ws, size_t ws_size,
                              hipStream_t stream) {
  const float* x = (const float*)d_in[0];
  const int* ei = (const int*)d_in[1];
  const float* fe_ws = (const float*)d_in[2];
  const float* fe_b = (const float*)d_in[3];
  const float* c0_ws = (const float*)d_in[4];
  const float* c0_b = (const float*)d_in[5];
  const float* cw = (const float*)d_in[6];
  const float* cb = (const float*)d_in[7];
  const float* fcw = (const float*)d_in[8];
  const float* fcb = (const float*)d_in[9];
  float* out = (float*)d_out;

  const int* row = ei;
  const int* colv = ei + NE;

  char* wp = (char*)d_ws;
  auto alloc = [&](size_t bytes) {
    char* p = wp;
    wp += (bytes + 511) & ~(size_t)511;
    return p;
  };
  int* degi = (int*)alloc(NN * 4);
  int* off = (int*)alloc((NN + 1) * 4);
  int* cursor = (int*)alloc(NN * 4);
  int* bsum = (int*)alloc(SCAN_B * 4);
  int* boff = (int*)alloc(SCAN_B * 4);
  float* dis = (float*)alloc(NN * 4);
  int* src = (int*)alloc((size_t)NE * 4);
  float* wgt = (float*)alloc((size_t)NE * 4);
  _Float16* wsT = (_Float16*)alloc((size_t)12 * 16384 * 2);
  float* px17 = (float*)alloc((size_t)NN * 17 * 4);
  _Float16* h16 = (_Float16*)alloc((size_t)NN * 16 * 2);
  _Float16* p16a = (_Float16*)alloc((size_t)NN * 16 * 2);
  _Float16* p16b = (_Float16*)alloc((size_t)NN * 16 * 2);
  _Float16* p16c = (_Float16*)alloc((size_t)NN * 16 * 2);
  _Float16* H0 = (_Float16*)alloc((size_t)NN * 128 * 2);
  _Float16* H1 = (_Float16*)alloc((size_t)NN * 128 * 2);
  _Float16* T1 = (_Float16*)alloc((size_t)NN * 128 * 2);
  _Float16* T2 = (_Float16*)alloc((size_t)NN * 128 * 2);
  _Float16* T3 = (_Float16*)alloc((size_t)NN * 128 * 2);

  // ---- graph prep ----
  hipMemsetAsync(degi, 0, NN * 4, stream);
  hipMemsetAsync(cursor, 0, NN * 4, stream);
  k_deg<<<(NE + 255) / 256, 256, 0, stream>>>(colv, degi);
  k_dis<<<(NN + 255) / 256, 256, 0, stream>>>(degi, dis);
  k_scan1<<<SCAN_B, 256, 0, stream>>>(degi, bsum);
  k_scan2<<<1, 128, 0, stream>>>(bsum, boff, off);
  k_scan3<<<SCAN_B, 256, 0, stream>>>(degi, boff, off);
  k_fill<<<(NE + 255) / 256, 256, 0, stream>>>(row, colv, dis, off, cursor, src, wgt);
  k_wprep<<<768, 256, 0, stream>>>(cw, wsT);

  // ---- featureEmbedding: h16 = x@W0 + prop(x)@W1 + b (fp16 out) ----
  k_mm16h<17, false, true><<<NN / 16, 256, 0, stream>>>(x, fe_ws, fe_b, h16);
  k_prop_small<17><<<NN, 64, 0, stream>>>(x, off, src, wgt, px17);
  k_mm16h<17, true, false><<<NN / 16, 256, 0, stream>>>(px17, fe_ws + 17 * 16, nullptr, h16);

  // ---- conv0 (16 -> 128, K=3, relu) -> H0 fp16 ----
  k_prop16h<<<NN / 8, 64, 0, stream>>>((const h2s*)h16, off, src, wgt, (h2s*)p16a);
  k_prop16h<<<NN / 8, 64, 0, stream>>>((const h2s*)p16a, off, src, wgt, (h2s*)p16b);
  k_prop16h<<<NN / 8, 64, 0, stream>>>((const h2s*)p16b, off, src, wgt, (h2s*)p16c);
  k_conv0_fused<<<NN / 32, 256, 0, stream>>>(h16, p16a, p16b, p16c, c0_ws, c0_b, H0);

  // ---- conv1..3 (128 -> 128, K=3): 3 props + 1 fused MFMA GEMM each ----
  _Float16* hin = H0;
  _Float16* hout = H1;
  int mgrid = (NN + 63) / 64;
  for (int l = 0; l < 3; ++l) {
    k_prop128h<<<NN, 64, 0, stream>>>((const h2s*)hin, off, src, wgt, (h2s*)T1);
    k_prop128h<<<NN, 64, 0, stream>>>((const h2s*)T1, off, src, wgt, (h2s*)T2);
    k_prop128h<<<NN, 64, 0, stream>>>((const h2s*)T2, off, src, wgt, (h2s*)T3);
    const _Float16* Wl = wsT + (size_t)l * 4 * 16384;
    const float* bl = cb + l * 128;
    if (l < 2)
      k_tag4_mfma<true><<<mgrid, 256, 0, stream>>>(hin, T1, T2, T3, Wl, bl, hout);
    else
      k_tag4_mfma<false><<<mgrid, 256, 0, stream>>>(hin, T1, T2, T3, Wl, bl, hout);
    _Float16* t = hin; hin = hout; hout = t;
  }

  // ---- fc ----
  k_fc<<<NN, 64, 0, stream>>>(hin, fcw, fcb, out);
}

// Round 4
// 1046.874 us; speedup vs baseline: 3.1118x; 1.2501x over previous
//
#include <hip/hip_runtime.h>

#define NN 100000
#define NE 1600000
#define SCAN_B 98  // 98*1024 >= NN

typedef _Float16 half8 __attribute__((ext_vector_type(8)));
typedef float f32x4 __attribute__((ext_vector_type(4)));
struct h2s { _Float16 x, y; };
struct h4s { _Float16 a, b, c, d; };

// ---------------- graph prep ----------------
__global__ void k_deg(const int* __restrict__ col, int* __restrict__ degi) {
  int e = blockIdx.x * blockDim.x + threadIdx.x;
  if (e < NE) atomicAdd(&degi[col[e]], 1);
}

__global__ void k_dis(const int* __restrict__ degi, float* __restrict__ dis) {
  int i = blockIdx.x * blockDim.x + threadIdx.x;
  if (i < NN) {
    int d = degi[i];
    dis[i] = d > 0 ? rsqrtf((float)d) : 0.0f;
  }
}

__global__ void k_scan1(const int* __restrict__ degi, int* __restrict__ bsum) {
  __shared__ int red[256];
  int t = threadIdx.x;
  int base = blockIdx.x * 1024 + t * 4;
  int s = 0;
#pragma unroll
  for (int u = 0; u < 4; ++u) {
    int i = base + u;
    if (i < NN) s += degi[i];
  }
  red[t] = s;
  __syncthreads();
  for (int o = 128; o; o >>= 1) {
    if (t < o) red[t] += red[t + o];
    __syncthreads();
  }
  if (t == 0) bsum[blockIdx.x] = red[0];
}

__global__ void k_scan2(const int* __restrict__ bsum, int* __restrict__ boff,
                        int* __restrict__ off) {
  __shared__ int sh[128];
  int t = threadIdx.x;  // 128
  int v = (t < SCAN_B) ? bsum[t] : 0;
  sh[t] = v;
  __syncthreads();
  for (int o = 1; o < 128; o <<= 1) {
    int u = (t >= o) ? sh[t - o] : 0;
    __syncthreads();
    sh[t] += u;
    __syncthreads();
  }
  if (t < SCAN_B) boff[t] = sh[t] - v;
  if (t == 127) off[NN] = sh[127];
}

__global__ void k_scan3(const int* __restrict__ degi, const int* __restrict__ boff,
                        int* __restrict__ off) {
  __shared__ int red[256];
  int t = threadIdx.x;
  int base = blockIdx.x * 1024 + t * 4;
  int d[4];
  int s = 0;
#pragma unroll
  for (int u = 0; u < 4; ++u) {
    int i = base + u;
    d[u] = (i < NN) ? degi[i] : 0;
    s += d[u];
  }
  red[t] = s;
  __syncthreads();
  for (int o = 1; o < 256; o <<= 1) {
    int u2 = (t >= o) ? red[t - o] : 0;
    __syncthreads();
    red[t] += u2;
    __syncthreads();
  }
  int pre = red[t] - s + boff[blockIdx.x];
#pragma unroll
  for (int u = 0; u < 4; ++u) {
    int i = base + u;
    if (i < NN) {
      off[i] = pre;
      pre += d[u];
    }
  }
}

__global__ void k_fill(const int* __restrict__ row, const int* __restrict__ col,
                       const float* __restrict__ dis, const int* __restrict__ off,
                       int* __restrict__ cursor, int* __restrict__ src,
                       float* __restrict__ wgt) {
  int e = blockIdx.x * blockDim.x + threadIdx.x;
  if (e < NE) {
    int c = col[e], r = row[e];
    int slot = off[c] + atomicAdd(&cursor[c], 1);
    src[slot] = r;
    wgt[slot] = dis[r] * dis[c];
  }
}

// convert+transpose conv weights: cw [12][128k][128n] f32 -> wt [12][128n][128k] f16
__global__ void k_wprep(const float* __restrict__ cw, _Float16* __restrict__ wt) {
  int i = blockIdx.x * 256 + threadIdx.x;
  if (i < 12 * 16384) {
    int mat = i >> 14;
    int rem = i & 16383;
    int k = rem >> 7;
    int n = rem & 127;
    wt[(mat << 14) | (n << 7) | k] = (_Float16)cw[i];
  }
}

// ---------------- propagation ----------------
template <int F>
__global__ void k_prop_small(const float* __restrict__ h, const int* __restrict__ off,
                             const int* __restrict__ src, const float* __restrict__ wgt,
                             float* __restrict__ out) {
  int node = blockIdx.x;
  int t = threadIdx.x;
  if (t >= F) return;
  int b = off[node], e = off[node + 1];
  float acc = 0.f;
  for (int j = b; j < e; ++j) acc += h[src[j] * F + t] * wgt[j];
  out[node * F + t] = acc;
}

__global__ void k_prop16h(const h2s* __restrict__ h, const int* __restrict__ off,
                          const int* __restrict__ src, const float* __restrict__ wgt,
                          h2s* __restrict__ out) {
  int t = threadIdx.x;  // 64
  int node = blockIdx.x * 8 + (t >> 3);
  int f = t & 7;
  int b = off[node], e = off[node + 1];
  float ax = 0.f, ay = 0.f;
  int j = b;
  for (; j + 2 <= e; j += 2) {
    int s0 = src[j], s1 = src[j + 1];
    float w0 = wgt[j], w1 = wgt[j + 1];
    h2s v0 = h[s0 * 8 + f];
    h2s v1 = h[s1 * 8 + f];
    ax = fmaf((float)v0.x, w0, fmaf((float)v1.x, w1, ax));
    ay = fmaf((float)v0.y, w0, fmaf((float)v1.y, w1, ay));
  }
  if (j < e) {
    int s = src[j];
    float w = wgt[j];
    h2s v = h[s * 8 + f];
    ax = fmaf((float)v.x, w, ax);
    ay = fmaf((float)v.y, w, ay);
  }
  h2s o;
  o.x = (_Float16)ax;
  o.y = (_Float16)ay;
  unsigned bits;
  __builtin_memcpy(&bits, &o, 4);
  __builtin_nontemporal_store(bits, (unsigned*)&out[node * 8 + f]);
}

__global__ void k_prop128h(const h2s* __restrict__ h, const int* __restrict__ off,
                           const int* __restrict__ src, const float* __restrict__ wgt,
                           h2s* __restrict__ out) {
  int node = blockIdx.x;
  int t = threadIdx.x;  // 64
  int b = off[node], e = off[node + 1];
  float ax = 0.f, ay = 0.f;
  int j = b;
  for (; j + 8 <= e; j += 8) {
    h2s v[8];
    float w[8];
#pragma unroll
    for (int u = 0; u < 8; ++u) {
      v[u] = h[src[j + u] * 64 + t];
      w[u] = wgt[j + u];
    }
#pragma unroll
    for (int u = 0; u < 8; ++u) {
      ax = fmaf((float)v[u].x, w[u], ax);
      ay = fmaf((float)v[u].y, w[u], ay);
    }
  }
  for (; j < e; ++j) {
    int s = src[j];
    float w = wgt[j];
    h2s v = h[s * 64 + t];
    ax = fmaf((float)v.x, w, ax);
    ay = fmaf((float)v.y, w, ay);
  }
  h2s o;
  o.x = (_Float16)ax;
  o.y = (_Float16)ay;
  unsigned bits;
  __builtin_memcpy(&bits, &o, 4);
  __builtin_nontemporal_store(bits, (unsigned*)&out[node * 64 + t]);
}

// ---------------- fused TAG layer GEMM (128->128, 4 sources, MFMA f16) ----------------
// Block = 256 thr (4 waves), each wave 32 rows -> block M-tile 128.
// s-outer: stage W_s (32 KB) into XOR-swizzled LDS, then 2-row-frag MFMA loop.
// Swizzle (granule involution): 16B granule g <-> g ^ ((g>>4)&7)  [byte ^= (n&7)<<4]
template <bool RELU>
__global__ __launch_bounds__(256) void k_tag4_mfma(
    const _Float16* __restrict__ A0, const _Float16* __restrict__ A1,
    const _Float16* __restrict__ A2, const _Float16* __restrict__ A3,
    const _Float16* __restrict__ Wt, const float* __restrict__ bias,
    _Float16* __restrict__ out) {
  __shared__ _Float16 Wl[16384];  // 32 KB
  int tid = threadIdx.x;
  int wid = tid >> 6;
  int lane = tid & 63;
  int r = lane & 15, kg = lane >> 4;
  int m0 = blockIdx.x * 128 + wid * 32;
  int row0 = min(m0 + r, NN - 1);
  int row1 = min(m0 + 16 + r, NN - 1);
  f32x4 acc0[8] = {}, acc1[8] = {};
  const _Float16* As[4] = {A0, A1, A2, A3};
#pragma unroll
  for (int s = 0; s < 4; ++s) {
    const float4* Wg = (const float4*)(Wt + (s << 14));  // 2048 granules of 16B
    __syncthreads();  // previous stage fully consumed
#pragma unroll
    for (int u = 0; u < 8; ++u) {
      int g = tid + u * 256;
      int sg = g ^ ((g >> 4) & 7);
      *(float4*)((char*)Wl + g * 16) = Wg[sg];
    }
    __syncthreads();
    const _Float16* A = As[s];
    half8 a0[4], a1[4];
#pragma unroll
    for (int kc = 0; kc < 4; ++kc) {
      int kbase = kc * 32 + kg * 8;
      a0[kc] = *(const half8*)&A[(size_t)row0 * 128 + kbase];
      a1[kc] = *(const half8*)&A[(size_t)row1 * 128 + kbase];
    }
#pragma unroll
    for (int kc = 0; kc < 4; ++kc) {
      int kb2 = (kc * 32 + kg * 8) * 2;
#pragma unroll
      for (int nb = 0; nb < 8; ++nb) {
        int n = nb * 16 + r;
        int ba = ((n << 8) + kb2) ^ ((n & 7) << 4);
        half8 b = *(const half8*)((const char*)Wl + ba);
        acc0[nb] = __builtin_amdgcn_mfma_f32_16x16x32_f16(a0[kc], b, acc0[nb], 0, 0, 0);
        acc1[nb] = __builtin_amdgcn_mfma_f32_16x16x32_f16(a1[kc], b, acc1[nb], 0, 0, 0);
      }
    }
  }
  int ccol = lane & 15;
#pragma unroll
  for (int h = 0; h < 2; ++h) {
    int crow0 = m0 + h * 16 + kg * 4;
#pragma unroll
    for (int nb = 0; nb < 8; ++nb) {
      int col = nb * 16 + ccol;
      float bv = bias[col];
      const f32x4& av = h ? acc1[nb] : acc0[nb];
#pragma unroll
      for (int e = 0; e < 4; ++e) {
        float v = av[e] + bv;
        if (RELU) v = fmaxf(v, 0.f);
        int rr = crow0 + e;
        if (rr < NN) out[(size_t)rr * 128 + col] = (_Float16)v;
      }
    }
  }
}

// ---------------- conv0 fused (4 fp16 sources 16-wide -> 128, relu, fp16 out) ----------------
__global__ __launch_bounds__(256) void k_conv0_fused(
    const _Float16* __restrict__ A0, const _Float16* __restrict__ A1,
    const _Float16* __restrict__ A2, const _Float16* __restrict__ A3,
    const float* __restrict__ W /*[4][16][128]*/, const float* __restrict__ bias,
    _Float16* __restrict__ out) {
  __shared__ float Wl[4 * 16 * 128];
  for (int i = threadIdx.x * 4; i < 4 * 16 * 128; i += 1024)
    *(float4*)&Wl[i] = *(const float4*)&W[i];
  __syncthreads();
  int r0 = blockIdx.x * 32 + (threadIdx.x >> 5) * 4;
  int c0 = (threadIdx.x & 31) * 4;
  float acc[4][4] = {};
  const _Float16* As[4] = {A0, A1, A2, A3};
#pragma unroll
  for (int s = 0; s < 4; ++s) {
    const _Float16* A = As[s];
    const float* Ws = &Wl[s * 2048];
#pragma unroll
    for (int k = 0; k < 16; k += 4) {
      float4 w0 = *(const float4*)&Ws[(k + 0) * 128 + c0];
      float4 w1 = *(const float4*)&Ws[(k + 1) * 128 + c0];
      float4 w2 = *(const float4*)&Ws[(k + 2) * 128 + c0];
      float4 w3 = *(const float4*)&Ws[(k + 3) * 128 + c0];
#pragma unroll
      for (int i = 0; i < 4; ++i) {
        h4s a4 = *(const h4s*)&A[(r0 + i) * 16 + k];
        float ax = (float)a4.a, ay = (float)a4.b, az = (float)a4.c, aw = (float)a4.d;
        acc[i][0] = fmaf(ax, w0.x, fmaf(ay, w1.x, fmaf(az, w2.x, fmaf(aw, w3.x, acc[i][0]))));
        acc[i][1] = fmaf(ax, w0.y, fmaf(ay, w1.y, fmaf(az, w2.y, fmaf(aw, w3.y, acc[i][1]))));
        acc[i][2] = fmaf(ax, w0.z, fmaf(ay, w1.z, fmaf(az, w2.z, fmaf(aw, w3.z, acc[i][2]))));
        acc[i][3] = fmaf(ax, w0.w, fmaf(ay, w1.w, fmaf(az, w2.w, fmaf(aw, w3.w, acc[i][3]))));
      }
    }
  }
#pragma unroll
  for (int i = 0; i < 4; ++i) {
    h4s o;
    o.a = (_Float16)fmaxf(acc[i][0] + bias[c0 + 0], 0.f);
    o.b = (_Float16)fmaxf(acc[i][1] + bias[c0 + 1], 0.f);
    o.c = (_Float16)fmaxf(acc[i][2] + bias[c0 + 2], 0.f);
    o.d = (_Float16)fmaxf(acc[i][3] + bias[c0 + 3], 0.f);
    *(h4s*)&out[(size_t)(r0 + i) * 128 + c0] = o;
  }
}

// ---------------- feature embedding GEMM (fp32 in, fp16 out, 16 cols) ----------------
template <int IN, bool ACCUM, bool BIAS>
__global__ void k_mm16h(const float* __restrict__ A, const float* __restrict__ W,
                        const float* __restrict__ bias, _Float16* __restrict__ C) {
  __shared__ float Wl[IN * 16];
  for (int i = threadIdx.x; i < IN * 16; i += 256) Wl[i] = W[i];
  __syncthreads();
  int r = blockIdx.x * 16 + (threadIdx.x >> 4);
  int c = threadIdx.x & 15;
  float acc = 0.f;
  for (int k = 0; k < IN; ++k) acc += A[r * IN + k] * Wl[k * 16 + c];
  int idx = r * 16 + c;
  if (BIAS) acc += bias[c];
  if (ACCUM) acc += (float)C[idx];
  C[idx] = (_Float16)acc;
}

__global__ void k_fc(const _Float16* __restrict__ h, const float* __restrict__ w,
                     const float* __restrict__ b, float* __restrict__ out) {
  int node = blockIdx.x;
  int t = threadIdx.x;  // 64
  float s = (float)h[node * 128 + t] * w[t] + (float)h[node * 128 + t + 64] * w[t + 64];
  for (int o = 32; o; o >>= 1) s += __shfl_down(s, o);
  if (t == 0) out[node] = s + b[0];
}

extern "C" void kernel_launch(void* const* d_in, const int* in_sizes, int n_in,
                              void* d_out, int out_size, void* d_ws, size_t ws_size,
                              hipStream_t stream) {
  const float* x = (const float*)d_in[0];
  const int* ei = (const int*)d_in[1];
  const float* fe_ws = (const float*)d_in[2];
  const float* fe_b = (const float*)d_in[3];
  const float* c0_ws = (const float*)d_in[4];
  const float* c0_b = (const float*)d_in[5];
  const float* cw = (const float*)d_in[6];
  const float* cb = (const float*)d_in[7];
  const float* fcw = (const float*)d_in[8];
  const float* fcb = (const float*)d_in[9];
  float* out = (float*)d_out;

  const int* row = ei;
  const int* colv = ei + NE;

  char* wp = (char*)d_ws;
  auto alloc = [&](size_t bytes) {
    char* p = wp;
    wp += (bytes + 511) & ~(size_t)511;
    return p;
  };
  int* degi = (int*)alloc(NN * 4);
  int* off = (int*)alloc((NN + 1) * 4);
  int* cursor = (int*)alloc(NN * 4);
  int* bsum = (int*)alloc(SCAN_B * 4);
  int* boff = (int*)alloc(SCAN_B * 4);
  float* dis = (float*)alloc(NN * 4);
  int* src = (int*)alloc((size_t)NE * 4);
  float* wgt = (float*)alloc((size_t)NE * 4);
  _Float16* wsT = (_Float16*)alloc((size_t)12 * 16384 * 2);
  float* px17 = (float*)alloc((size_t)NN * 17 * 4);
  _Float16* h16 = (_Float16*)alloc((size_t)NN * 16 * 2);
  _Float16* p16a = (_Float16*)alloc((size_t)NN * 16 * 2);
  _Float16* p16b = (_Float16*)alloc((size_t)NN * 16 * 2);
  _Float16* p16c = (_Float16*)alloc((size_t)NN * 16 * 2);
  _Float16* H0 = (_Float16*)alloc((size_t)NN * 128 * 2);
  _Float16* H1 = (_Float16*)alloc((size_t)NN * 128 * 2);
  _Float16* T1 = (_Float16*)alloc((size_t)NN * 128 * 2);
  _Float16* T2 = (_Float16*)alloc((size_t)NN * 128 * 2);
  _Float16* T3 = (_Float16*)alloc((size_t)NN * 128 * 2);

  // ---- graph prep ----
  hipMemsetAsync(degi, 0, NN * 4, stream);
  hipMemsetAsync(cursor, 0, NN * 4, stream);
  k_deg<<<(NE + 255) / 256, 256, 0, stream>>>(colv, degi);
  k_dis<<<(NN + 255) / 256, 256, 0, stream>>>(degi, dis);
  k_scan1<<<SCAN_B, 256, 0, stream>>>(degi, bsum);
  k_scan2<<<1, 128, 0, stream>>>(bsum, boff, off);
  k_scan3<<<SCAN_B, 256, 0, stream>>>(degi, boff, off);
  k_fill<<<(NE + 255) / 256, 256, 0, stream>>>(row, colv, dis, off, cursor, src, wgt);
  k_wprep<<<768, 256, 0, stream>>>(cw, wsT);

  // ---- featureEmbedding: h16 = x@W0 + prop(x)@W1 + b (fp16 out) ----
  k_mm16h<17, false, true><<<NN / 16, 256, 0, stream>>>(x, fe_ws, fe_b, h16);
  k_prop_small<17><<<NN, 64, 0, stream>>>(x, off, src, wgt, px17);
  k_mm16h<17, true, false><<<NN / 16, 256, 0, stream>>>(px17, fe_ws + 17 * 16, nullptr, h16);

  // ---- conv0 (16 -> 128, K=3, relu) -> H0 fp16 ----
  k_prop16h<<<NN / 8, 64, 0, stream>>>((const h2s*)h16, off, src, wgt, (h2s*)p16a);
  k_prop16h<<<NN / 8, 64, 0, stream>>>((const h2s*)p16a, off, src, wgt, (h2s*)p16b);
  k_prop16h<<<NN / 8, 64, 0, stream>>>((const h2s*)p16b, off, src, wgt, (h2s*)p16c);
  k_conv0_fused<<<NN / 32, 256, 0, stream>>>(h16, p16a, p16b, p16c, c0_ws, c0_b, H0);

  // ---- conv1..3 (128 -> 128, K=3): 3 props + 1 fused MFMA GEMM each ----
  _Float16* hin = H0;
  _Float16* hout = H1;
  int mgrid = (NN + 127) / 128;
  for (int l = 0; l < 3; ++l) {
    k_prop128h<<<NN, 64, 0, stream>>>((const h2s*)hin, off, src, wgt, (h2s*)T1);
    k_prop128h<<<NN, 64, 0, stream>>>((const h2s*)T1, off, src, wgt, (h2s*)T2);
    k_prop128h<<<NN, 64, 0, stream>>>((const h2s*)T2, off, src, wgt, (h2s*)T3);
    const _Float16* Wl = wsT + (size_t)l * 4 * 16384;
    const float* bl = cb + l * 128;
    if (l < 2)
      k_tag4_mfma<true><<<mgrid, 256, 0, stream>>>(hin, T1, T2, T3, Wl, bl, hout);
    else
      k_tag4_mfma<false><<<mgrid, 256, 0, stream>>>(hin, T1, T2, T3, Wl, bl, hout);
    _Float16* t = hin; hin = hout; hout = t;
  }

  // ---- fc ----
  k_fc<<<NN, 64, 0, stream>>>(hin, fcw, fcb, out);
}